// Round 16
// baseline (514.458 us; speedup 1.0000x reference)
//
#include <hip/hip_runtime.h>
#include <hip/hip_bf16.h>
#include <stdint.h>

// Problem constants
#define BB 8
#define SS 1024
#define HH 16
#define DHD 64
#define DD 1024

typedef __attribute__((ext_vector_type(8))) short bf16x8;
typedef __attribute__((ext_vector_type(4))) float f32x4;

__device__ __forceinline__ unsigned short f2bf(float f) {
  unsigned u = __builtin_bit_cast(unsigned, f);
  u += 0x7fffu + ((u >> 16) & 1u);   // round-to-nearest-even
  return (unsigned short)(u >> 16);
}

// XOR swizzle for 128B-row LDS tiles: xor byte bits[6:4] with row bits[2:0].
__device__ __forceinline__ unsigned swz(unsigned a) { return a ^ ((a >> 3) & 0x70u); }

#define GLOAD16(gp, lp)                                                        \
  __builtin_amdgcn_global_load_lds(                                            \
      (const __attribute__((address_space(1))) unsigned int*)(gp),             \
      (__attribute__((address_space(3))) unsigned int*)(lp), 16, 0, 0)

#define MFMA16(a, b, c) __builtin_amdgcn_mfma_f32_16x16x32_bf16(a, b, c, 0, 0, 0)

// ---------------------------------------------------------------- K1: x -> bf16
__global__ __launch_bounds__(256) void cvt_x_kernel(const float* __restrict__ x,
                                                    unsigned short* __restrict__ xb) {
  int i = blockIdx.x * 256 + threadIdx.x;
  float4 v = ((const float4*)x)[i];
  ushort4 o;
  o.x = f2bf(v.x); o.y = f2bf(v.y); o.z = f2bf(v.z); o.w = f2bf(v.w);
  ((ushort4*)xb)[i] = o;
}

// ------------------------------------------- K1b: transpose weights -> bf16 [n][k]
__global__ __launch_bounds__(256) void transpose_w_kernel(
    const float* __restrict__ w0, const float* __restrict__ w1,
    const float* __restrict__ w2, const float* __restrict__ w3,
    unsigned short* __restrict__ o0, unsigned short* __restrict__ o1,
    unsigned short* __restrict__ o2, unsigned short* __restrict__ o3) {
  __shared__ float tile[32][33];
  const float* src; unsigned short* dst;
  if (blockIdx.z == 0)      { src = w0; dst = o0; }
  else if (blockIdx.z == 1) { src = w1; dst = o1; }
  else if (blockIdx.z == 2) { src = w2; dst = o2; }
  else                      { src = w3; dst = o3; }
  int n0 = blockIdx.x * 32, k0 = blockIdx.y * 32;
  int tx = threadIdx.x, ty = threadIdx.y;   // block (32,8)
#pragma unroll
  for (int j = 0; j < 32; j += 8)
    tile[ty + j][tx] = src[(size_t)(k0 + ty + j) * DD + n0 + tx];
  __syncthreads();
#pragma unroll
  for (int j = 0; j < 32; j += 8)
    dst[(size_t)(n0 + ty + j) * DD + k0 + tx] = f2bf(tile[tx][ty + j]);
}

// ------------------------------------------------- K2: projections GEMM (q,k,v)
// XCD-temporal 1-D mapping: m = (bid&7)*8 + (bid>>3)/24, ny = (bid>>3)%24
__global__ __launch_bounds__(256) void proj_gemm_kernel(
    const unsigned short* __restrict__ xb,
    const unsigned short* __restrict__ wqt, const unsigned short* __restrict__ wkt,
    const unsigned short* __restrict__ wvt,
    const float* __restrict__ bq, const float* __restrict__ bk, const float* __restrict__ bv,
    float* __restrict__ qo, float* __restrict__ ko, float* __restrict__ vo,
    unsigned short* __restrict__ qb, unsigned short* __restrict__ kbf,
    unsigned short* __restrict__ vt) {
  __shared__ __align__(128) unsigned short smem[2 * 128 * 64];  // As | Bs (32 KB)
  unsigned short* As = smem;
  unsigned short* Bs = smem + 128 * 64;
  const int tid = threadIdx.x, lane = tid & 63, w = tid >> 6;
  const int wr = (w >> 1) * 64, wc = (w & 1) * 64;
  const int bid = blockIdx.x;
  const int mblk = (bid & 7) * 8 + (bid >> 3) / 24;
  const int ny = (bid >> 3) % 24;
  const int m0 = mblk * 128;
  const int mat = ny >> 3;
  const int n0 = (ny & 7) * 128;
  const unsigned short* Bg = (mat == 0) ? wqt : (mat == 1) ? wkt : wvt;
  const float* bias = (mat == 0) ? bq : (mat == 1) ? bk : bv;

  f32x4 acc[4][4];
  f32x4 z4 = {0.f, 0.f, 0.f, 0.f};
#pragma unroll
  for (int i = 0; i < 4; ++i)
#pragma unroll
    for (int j = 0; j < 4; ++j) acc[i][j] = z4;

  for (int kt = 0; kt < 1024; kt += 64) {
    __syncthreads();
#pragma unroll
    for (int i = 0; i < 4; ++i) {
      unsigned obase = (unsigned)(w * 4096 + i * 1024);
      unsigned a = swz(obase + (unsigned)lane * 16);
      GLOAD16((const char*)xb + ((size_t)(m0 + (int)(a >> 7)) * 1024 + kt) * 2 + (a & 127),
              (char*)As + obase);
      GLOAD16((const char*)Bg + ((size_t)(n0 + (int)(a >> 7)) * 1024 + kt) * 2 + (a & 127),
              (char*)Bs + obase);
    }
    __syncthreads();
#pragma unroll
    for (int ks = 0; ks < 2; ++ks) {
      bf16x8 af[4], bfr[4];
#pragma unroll
      for (int mi = 0; mi < 4; ++mi) {
        unsigned a = (unsigned)((wr + mi * 16 + (lane & 15)) * 128 + ks * 64 + ((lane >> 4) * 16));
        af[mi] = *(const bf16x8*)((const char*)As + swz(a));
      }
#pragma unroll
      for (int ni = 0; ni < 4; ++ni) {
        unsigned a = (unsigned)((wc + ni * 16 + (lane & 15)) * 128 + ks * 64 + ((lane >> 4) * 16));
        bfr[ni] = *(const bf16x8*)((const char*)Bs + swz(a));
      }
#pragma unroll
      for (int mi = 0; mi < 4; ++mi)
#pragma unroll
        for (int ni = 0; ni < 4; ++ni)
          acc[mi][ni] = MFMA16(af[mi], bfr[ni], acc[mi][ni]);
    }
  }

  float* fo = (mat == 0) ? qo : (mat == 1) ? ko : vo;
  __syncthreads();  // K-loop LDS reads done; smem reusable for V transpose bounce
  unsigned short* T = smem;  // [dh_local][s_local^swz] 128x128 bf16 = 32 KB

#pragma unroll
  for (int mi = 0; mi < 4; ++mi)
#pragma unroll
    for (int ni = 0; ni < 4; ++ni) {
      int col = n0 + wc + ni * 16 + (lane & 15);
      float bs = bias[col];
#pragma unroll
      for (int r = 0; r < 4; ++r) {
        int row = m0 + wr + mi * 16 + ((lane >> 4) << 2) + r;
        float v = acc[mi][ni][r] + bs;
        int b = row >> 10, s = row & 1023, h = col >> 6, dh = col & 63;
        size_t bh = (size_t)(b * HH + h);
        __builtin_nontemporal_store(v, &fo[(bh * SS + s) * DHD + dh]);
        if (mat == 2) {
          int sl = wr + mi * 16 + ((lane >> 4) << 2) + r;
          int dl = wc + ni * 16 + (lane & 15);
          T[dl * 128 + (sl ^ ((dl & 7) << 4))] = f2bf(v);
        } else if (mat == 0) {
          qb[(bh * SS + s) * DHD + dh] = f2bf(v * 0.125f);  // pre-scaled by 1/sqrt(64)
        } else {
          kbf[(bh * SS + s) * DHD + dh] = f2bf(v);
        }
      }
    }

  if (mat == 2) {
    __syncthreads();
    int row = tid >> 1;
    int half = tid & 1;
    int colg = n0 + row;
    int h2 = colg >> 6, dh2 = colg & 63;
    int b = m0 >> 10;
    int sg0 = (m0 & 1023) + half * 64;
    unsigned short* dst = vt + (((size_t)(b * HH + h2)) * DHD + dh2) * SS + sg0;
#pragma unroll
    for (int j = 0; j < 8; ++j) {
      int sc = half * 64 + j * 8;
      bf16x8 vv = *(const bf16x8*)&T[row * 128 + (sc ^ ((row & 7) << 4))];
      *(bf16x8*)(dst + j * 8) = vv;
    }
  }
}

// ------------------------------- K3: fused attention, QBLK=128 (8 waves, 512 thr)
// Each staged K/V tile now serves 128 q-rows (was 64): staging traffic and
// barrier count per output element halve in BOTH passes. Per-wave algebra
// (16 q-rows, q15/G layout, swizzles, deferred stores, exact mask numerics)
// unchanged from r15. LDS 36KB.
__global__ __launch_bounds__(512) void attn_kernel(
    const unsigned short* __restrict__ qb, const unsigned short* __restrict__ kb,
    const unsigned short* __restrict__ vt, const float* __restrict__ mask,
    float* __restrict__ qk_out, float* __restrict__ attn_out,
    unsigned short* __restrict__ zb) {
  __shared__ __align__(128) unsigned short sbuf[16384];   // 32 KB union
  __shared__ __align__(16) float mbuf[SS];                // 4 KB

  const int tid = threadIdx.x, lane = tid & 63, w = tid >> 6;  // w = 0..7
  const int fid = blockIdx.x;
  const int s_ = fid >> 3;
  const int qt = s_ & 7;                       // 8 q-tiles of 128 rows
  const int bh = (fid & 7) + 8 * (s_ >> 3);
  const int b = bh >> 4, h = bh & 15;
  const int r0 = qt * 128 + w * 16;
  const int q15 = lane & 15, G = lane >> 4;

  if (tid < 256) ((float4*)mbuf)[tid] = ((const float4*)(mask + (size_t)b * SS))[tid];
  __syncthreads();

  bf16x8 aq[2];
  {
    const unsigned short* p = qb + (size_t)bh * SS * DHD + (size_t)(r0 + q15) * DHD + G * 8;
    aq[0] = *(const bf16x8*)p;
    aq[1] = *(const bf16x8*)(p + 32);
  }
  const float mq = mbuf[r0 + q15];

  const unsigned short* kbase = kb + (size_t)bh * SS * DHD;
  const char* vbase = (const char*)(vt + (size_t)bh * DHD * SS);
  float* qrow = qk_out + (size_t)bh * SS * SS + (size_t)(r0 + q15) * SS;
  float* arow = attn_out + (size_t)bh * SS * SS + (size_t)(r0 + q15) * SS;

  float m_run = -INFINITY, l_run = 0.f;

  // ---------------- pass 1: QK^T (KVBLK=128) -> qk (nt, deferred), online (m,l)
  {
    f32x4 dq[8];   // deferred qk tile (held one tile)
    for (int kt = 0; kt < 8; ++kt) {
      int k0 = kt * 128;
      __syncthreads();
#pragma unroll
      for (int i = 0; i < 2; ++i) {   // stage K tile: 128 rows x 64 cols (16 KB)
        unsigned obase = (unsigned)(w * 2048 + i * 1024);
        unsigned a = swz(obase + (unsigned)lane * 16);
        GLOAD16((const char*)(kbase + (size_t)k0 * 64) + a, (char*)sbuf + obase);
      }
      __syncthreads();
      // issue PREVIOUS tile's qk stores now: full compute window to retire
      if (kt > 0) {
        int p0 = (kt - 1) * 128 + G * 4;
#pragma unroll
        for (int ct = 0; ct < 8; ++ct)
          __builtin_nontemporal_store(dq[ct], (f32x4*)(qrow + p0 + ct * 16));
      }
      f32x4 sm[8];
#pragma unroll
      for (int ct = 0; ct < 8; ++ct) {
        f32x4 acc = {0.f, 0.f, 0.f, 0.f};
#pragma unroll
        for (int ks = 0; ks < 2; ++ks) {
          unsigned a = (unsigned)((ct * 16 + q15) * 128 + ks * 64 + G * 16);
          bf16x8 bk = *(const bf16x8*)((const char*)sbuf + swz(a));
          acc = MFMA16(bk, aq[ks], acc);   // swapped: row=k, col=q
        }
        dq[ct] = acc;
        int c0 = k0 + ct * 16 + G * 4;
        float4 mk4 = *(const float4*)(mbuf + c0);
#pragma unroll
        for (int r = 0; r < 4; ++r) {
          float t = fminf(mq + ((const float*)&mk4)[r], 1.f);
          sm[ct][r] = acc[r] + t * (-1.0e9f);
        }
      }
      float mx = sm[0][0];
#pragma unroll
      for (int ct = 0; ct < 8; ++ct)
#pragma unroll
        for (int r = 0; r < 4; ++r) mx = fmaxf(mx, sm[ct][r]);
      mx = fmaxf(mx, __shfl_xor(mx, 16, 64));
      mx = fmaxf(mx, __shfl_xor(mx, 32, 64));
      float m_new = fmaxf(m_run, mx);
      float es = 0.f;
#pragma unroll
      for (int ct = 0; ct < 8; ++ct)
#pragma unroll
        for (int r = 0; r < 4; ++r) es += __expf(sm[ct][r] - m_new);
      es += __shfl_xor(es, 16, 64);
      es += __shfl_xor(es, 32, 64);
      l_run = l_run * __expf(m_run - m_new) + es;
      m_run = m_new;
    }
    // tail: last tile's qk stores
    int p0 = 7 * 128 + G * 4;
#pragma unroll
    for (int ct = 0; ct < 8; ++ct)
      __builtin_nontemporal_store(dq[ct], (f32x4*)(qrow + p0 + ct * 16));
  }

  const float inv_l = 1.0f / l_run;

  // ---------------- pass 2: recompute (KVBLK=64) -> attn (nt, deferred), PV
  f32x4 zacc[4];
#pragma unroll
  for (int dt = 0; dt < 4; ++dt) zacc[dt] = (f32x4){0.f, 0.f, 0.f, 0.f};

  unsigned short* kb2 = sbuf;                     // 8 KB
  unsigned short* vb2 = sbuf + 4096;              // 8 KB
  unsigned short* pw  = sbuf + 8192 + w * 1024;   // 2 KB per wave (8 waves, 16 KB)
  const unsigned pswz = (unsigned)((q15 & 14) << 3);

  f32x4 da[4];   // deferred attn tile
  for (int kt = 0; kt < 16; ++kt) {
    int k0 = kt * 64;
    __syncthreads();
    {   // stage K and V: 8 KB each, exactly one GLOAD16 round at 512 threads
      unsigned obase = (unsigned)(w * 1024);
      unsigned a = swz(obase + (unsigned)lane * 16);
      GLOAD16((const char*)(kbase + (size_t)k0 * 64) + a, (char*)kb2 + obase);
      GLOAD16(vbase + (size_t)(a >> 7) * (SS * 2) + (size_t)k0 * 2 + (a & 127),
              (char*)vb2 + obase);
    }
    __syncthreads();
    // issue PREVIOUS tile's attn stores now
    if (kt > 0) {
      int p0 = (kt - 1) * 64 + G * 4;
#pragma unroll
      for (int ct = 0; ct < 4; ++ct)
        __builtin_nontemporal_store(da[ct], (f32x4*)(arow + p0 + ct * 16));
    }
#pragma unroll
    for (int ct = 0; ct < 4; ++ct) {
      f32x4 acc = {0.f, 0.f, 0.f, 0.f};
#pragma unroll
      for (int ks = 0; ks < 2; ++ks) {
        unsigned a = (unsigned)((ct * 16 + q15) * 128 + ks * 64 + G * 16);
        bf16x8 bk = *(const bf16x8*)((const char*)kb2 + swz(a));
        acc = MFMA16(bk, aq[ks], acc);
      }
      int c0 = k0 + ct * 16 + G * 4;
      float4 mk4 = *(const float4*)(mbuf + c0);
      f32x4 pn;
#pragma unroll
      for (int r = 0; r < 4; ++r) {
        float t = fminf(mq + ((const float*)&mk4)[r], 1.f);
        pn[r] = __expf(acc[r] + t * (-1.0e9f) - m_run) * inv_l;
      }
      da[ct] = pn;
      unsigned u0 = (unsigned)f2bf(pn[0]) | ((unsigned)f2bf(pn[1]) << 16);
      unsigned u1 = (unsigned)f2bf(pn[2]) | ((unsigned)f2bf(pn[3]) << 16);
      uint2 pkd = {u0, u1};
      *(uint2*)((char*)pw + (((unsigned)(q15 * 128 + ct * 32 + G * 8)) ^ pswz)) = pkd;
    }
    // PV: A-frag = P[q=lane&15][k=G*8..G*8+7]
    bf16x8 pa[2];
#pragma unroll
    for (int ks = 0; ks < 2; ++ks)
      pa[ks] = *(const bf16x8*)((char*)pw + (((unsigned)(q15 * 128 + ks * 64 + G * 16)) ^ pswz));
#pragma unroll
    for (int dt = 0; dt < 4; ++dt) {
#pragma unroll
      for (int ks = 0; ks < 2; ++ks) {
        unsigned av = (unsigned)((dt * 16 + q15) * 128 + ks * 64 + G * 16);
        bf16x8 bv = *(const bf16x8*)((const char*)vb2 + swz(av));
        zacc[dt] = MFMA16(pa[ks], bv, zacc[dt]);
      }
    }
  }
  // tail: last tile's attn stores
  {
    int p0 = 15 * 64 + G * 4;
#pragma unroll
    for (int ct = 0; ct < 4; ++ct)
      __builtin_nontemporal_store(da[ct], (f32x4*)(arow + p0 + ct * 16));
  }

  // z epilogue: rows = r0 + G*4 + r, col = dt*16 + q15
#pragma unroll
  for (int dt = 0; dt < 4; ++dt)
#pragma unroll
    for (int r = 0; r < 4; ++r) {
      int srow = r0 + G * 4 + r;
      int dcol = dt * 16 + q15;
      zb[((size_t)b * SS + srow) * DD + h * 64 + dcol] = f2bf(zacc[dt][r]);
    }
}

// ---------------------------------------------------- K4: out = z @ wo + bo
__global__ __launch_bounds__(256) void out_gemm_kernel(
    const unsigned short* __restrict__ zb, const unsigned short* __restrict__ wot,
    const float* __restrict__ bo, float* __restrict__ outp) {
  __shared__ __align__(128) unsigned short As[128 * 64];
  __shared__ __align__(128) unsigned short Bs[128 * 64];
  const int tid = threadIdx.x, lane = tid & 63, w = tid >> 6;
  const int wr = (w >> 1) * 64, wc = (w & 1) * 64;
  const int m0 = blockIdx.x * 128;
  const int n0 = blockIdx.y * 128;

  f32x4 acc[4][4];
  f32x4 z4 = {0.f, 0.f, 0.f, 0.f};
#pragma unroll
  for (int i = 0; i < 4; ++i)
#pragma unroll
    for (int j = 0; j < 4; ++j) acc[i][j] = z4;

  for (int kt = 0; kt < 1024; kt += 64) {
    __syncthreads();
#pragma unroll
    for (int i = 0; i < 4; ++i) {
      unsigned obase = (unsigned)(w * 4096 + i * 1024);
      unsigned a = swz(obase + (unsigned)lane * 16);
      GLOAD16((const char*)zb + ((size_t)(m0 + (int)(a >> 7)) * 1024 + kt) * 2 + (a & 127),
              (char*)As + obase);
      GLOAD16((const char*)wot + ((size_t)(n0 + (int)(a >> 7)) * 1024 + kt) * 2 + (a & 127),
              (char*)Bs + obase);
    }
    __syncthreads();
#pragma unroll
    for (int ks = 0; ks < 2; ++ks) {
      bf16x8 af[4], bfr[4];
#pragma unroll
      for (int mi = 0; mi < 4; ++mi) {
        unsigned a = (unsigned)((wr + mi * 16 + (lane & 15)) * 128 + ks * 64 + ((lane >> 4) * 16));
        af[mi] = *(const bf16x8*)((const char*)As + swz(a));
      }
#pragma unroll
      for (int ni = 0; ni < 4; ++ni) {
        unsigned a = (unsigned)((wc + ni * 16 + (lane & 15)) * 128 + ks * 64 + ((lane >> 4) * 16));
        bfr[ni] = *(const bf16x8*)((const char*)Bs + swz(a));
      }
#pragma unroll
      for (int mi = 0; mi < 4; ++mi)
#pragma unroll
        for (int ni = 0; ni < 4; ++ni)
          acc[mi][ni] = MFMA16(af[mi], bfr[ni], acc[mi][ni]);
    }
  }
#pragma unroll
  for (int mi = 0; mi < 4; ++mi)
#pragma unroll
    for (int ni = 0; ni < 4; ++ni) {
      int col = n0 + wc + ni * 16 + (lane & 15);
      float bs = bo[col];
#pragma unroll
      for (int r = 0; r < 4; ++r) {
        int row = m0 + wr + mi * 16 + ((lane >> 4) << 2) + r;
        __builtin_nontemporal_store(acc[mi][ni][r] + bs, &outp[(size_t)row * DD + col]);
      }
    }
}

// ------------------------------------------------------------------ launcher
extern "C" void kernel_launch(void* const* d_in, const int* in_sizes, int n_in,
                              void* d_out, int out_size, void* d_ws, size_t ws_size,
                              hipStream_t stream) {
  const float* x    = (const float*)d_in[0];
  const float* mask = (const float*)d_in[1];
  const float* wq_w = (const float*)d_in[2];
  const float* wq_b = (const float*)d_in[3];
  const float* wk_w = (const float*)d_in[4];
  const float* wk_b = (const float*)d_in[5];
  const float* wv_w = (const float*)d_in[6];
  const float* wv_b = (const float*)d_in[7];
  const float* wo_w = (const float*)d_in[8];
  const float* wo_b = (const float*)d_in[9];

  float* outp = (float*)d_out;
  float* attn = outp + (size_t)8388608;
  float* qk   = attn + (size_t)134217728;
  float* qo   = qk + (size_t)134217728;
  float* ko   = qo + (size_t)8388608;
  float* vo   = ko + (size_t)8388608;

  char* ws = (char*)d_ws;
  unsigned short* xb  = (unsigned short*)(ws + 0);
  unsigned short* wqt = (unsigned short*)(ws + 16777216);
  unsigned short* wkt = (unsigned short*)(ws + 18874368);
  unsigned short* wvt = (unsigned short*)(ws + 20971520);
  unsigned short* wot = (unsigned short*)(ws + 23068672);
  unsigned short* qb  = (unsigned short*)(ws + 25165824);
  unsigned short* kb  = (unsigned short*)(ws + 41943040);
  unsigned short* vt  = (unsigned short*)(ws + 58720256);
  unsigned short* zb  = (unsigned short*)(ws + 75497472);

  cvt_x_kernel<<<8192, 256, 0, stream>>>(x, xb);
  transpose_w_kernel<<<dim3(32, 32, 4), dim3(32, 8), 0, stream>>>(
      wq_w, wk_w, wv_w, wo_w, wqt, wkt, wvt, wot);
  proj_gemm_kernel<<<1536, 256, 0, stream>>>(
      xb, wqt, wkt, wvt, wq_b, wk_b, wv_b, qo, ko, vo, qb, kb, vt);
  attn_kernel<<<1024, 512, 0, stream>>>(qb, kb, vt, mask, qk, attn, zb);
  out_gemm_kernel<<<dim3(64, 8), 256, 0, stream>>>(zb, wot, wo_b, outp);
}

// Round 17
// 461.275 us; speedup vs baseline: 1.1153x; 1.1153x over previous
//
#include <hip/hip_runtime.h>
#include <hip/hip_bf16.h>
#include <stdint.h>

// Problem constants
#define BB 8
#define SS 1024
#define HH 16
#define DHD 64
#define DD 1024

typedef __attribute__((ext_vector_type(8))) short bf16x8;
typedef __attribute__((ext_vector_type(4))) float f32x4;

__device__ __forceinline__ unsigned short f2bf(float f) {
  unsigned u = __builtin_bit_cast(unsigned, f);
  u += 0x7fffu + ((u >> 16) & 1u);   // round-to-nearest-even
  return (unsigned short)(u >> 16);
}

// XOR swizzle for 128B-row LDS tiles: xor byte bits[6:4] with row bits[2:0].
__device__ __forceinline__ unsigned swz(unsigned a) { return a ^ ((a >> 3) & 0x70u); }

#define GLOAD16(gp, lp)                                                        \
  __builtin_amdgcn_global_load_lds(                                            \
      (const __attribute__((address_space(1))) unsigned int*)(gp),             \
      (__attribute__((address_space(3))) unsigned int*)(lp), 16, 0, 0)

#define MFMA16(a, b, c) __builtin_amdgcn_mfma_f32_16x16x32_bf16(a, b, c, 0, 0, 0)

// ---------------------------------------------------------------- K1: x -> bf16
__global__ __launch_bounds__(256) void cvt_x_kernel(const float* __restrict__ x,
                                                    unsigned short* __restrict__ xb) {
  int i = blockIdx.x * 256 + threadIdx.x;
  float4 v = ((const float4*)x)[i];
  ushort4 o;
  o.x = f2bf(v.x); o.y = f2bf(v.y); o.z = f2bf(v.z); o.w = f2bf(v.w);
  ((ushort4*)xb)[i] = o;
}

// ------------------------------------------- K1b: transpose weights -> bf16 [n][k]
__global__ __launch_bounds__(256) void transpose_w_kernel(
    const float* __restrict__ w0, const float* __restrict__ w1,
    const float* __restrict__ w2, const float* __restrict__ w3,
    unsigned short* __restrict__ o0, unsigned short* __restrict__ o1,
    unsigned short* __restrict__ o2, unsigned short* __restrict__ o3) {
  __shared__ float tile[32][33];
  const float* src; unsigned short* dst;
  if (blockIdx.z == 0)      { src = w0; dst = o0; }
  else if (blockIdx.z == 1) { src = w1; dst = o1; }
  else if (blockIdx.z == 2) { src = w2; dst = o2; }
  else                      { src = w3; dst = o3; }
  int n0 = blockIdx.x * 32, k0 = blockIdx.y * 32;
  int tx = threadIdx.x, ty = threadIdx.y;   // block (32,8)
#pragma unroll
  for (int j = 0; j < 32; j += 8)
    tile[ty + j][tx] = src[(size_t)(k0 + ty + j) * DD + n0 + tx];
  __syncthreads();
#pragma unroll
  for (int j = 0; j < 32; j += 8)
    dst[(size_t)(n0 + ty + j) * DD + k0 + tx] = f2bf(tile[tx][ty + j]);
}

// ------------------------------------------------- K2: projections GEMM (q,k,v)
// XCD-temporal 1-D mapping: m = (bid&7)*8 + (bid>>3)/24, ny = (bid>>3)%24
__global__ __launch_bounds__(256) void proj_gemm_kernel(
    const unsigned short* __restrict__ xb,
    const unsigned short* __restrict__ wqt, const unsigned short* __restrict__ wkt,
    const unsigned short* __restrict__ wvt,
    const float* __restrict__ bq, const float* __restrict__ bk, const float* __restrict__ bv,
    float* __restrict__ qo, float* __restrict__ ko, float* __restrict__ vo,
    unsigned short* __restrict__ qb, unsigned short* __restrict__ kbf,
    unsigned short* __restrict__ vt) {
  __shared__ __align__(128) unsigned short smem[2 * 128 * 64];  // As | Bs (32 KB)
  unsigned short* As = smem;
  unsigned short* Bs = smem + 128 * 64;
  const int tid = threadIdx.x, lane = tid & 63, w = tid >> 6;
  const int wr = (w >> 1) * 64, wc = (w & 1) * 64;
  const int bid = blockIdx.x;
  const int mblk = (bid & 7) * 8 + (bid >> 3) / 24;
  const int ny = (bid >> 3) % 24;
  const int m0 = mblk * 128;
  const int mat = ny >> 3;
  const int n0 = (ny & 7) * 128;
  const unsigned short* Bg = (mat == 0) ? wqt : (mat == 1) ? wkt : wvt;
  const float* bias = (mat == 0) ? bq : (mat == 1) ? bk : bv;

  f32x4 acc[4][4];
  f32x4 z4 = {0.f, 0.f, 0.f, 0.f};
#pragma unroll
  for (int i = 0; i < 4; ++i)
#pragma unroll
    for (int j = 0; j < 4; ++j) acc[i][j] = z4;

  for (int kt = 0; kt < 1024; kt += 64) {
    __syncthreads();
#pragma unroll
    for (int i = 0; i < 4; ++i) {
      unsigned obase = (unsigned)(w * 4096 + i * 1024);
      unsigned a = swz(obase + (unsigned)lane * 16);
      GLOAD16((const char*)xb + ((size_t)(m0 + (int)(a >> 7)) * 1024 + kt) * 2 + (a & 127),
              (char*)As + obase);
      GLOAD16((const char*)Bg + ((size_t)(n0 + (int)(a >> 7)) * 1024 + kt) * 2 + (a & 127),
              (char*)Bs + obase);
    }
    __syncthreads();
#pragma unroll
    for (int ks = 0; ks < 2; ++ks) {
      bf16x8 af[4], bfr[4];
#pragma unroll
      for (int mi = 0; mi < 4; ++mi) {
        unsigned a = (unsigned)((wr + mi * 16 + (lane & 15)) * 128 + ks * 64 + ((lane >> 4) * 16));
        af[mi] = *(const bf16x8*)((const char*)As + swz(a));
      }
#pragma unroll
      for (int ni = 0; ni < 4; ++ni) {
        unsigned a = (unsigned)((wc + ni * 16 + (lane & 15)) * 128 + ks * 64 + ((lane >> 4) * 16));
        bfr[ni] = *(const bf16x8*)((const char*)Bs + swz(a));
      }
#pragma unroll
      for (int mi = 0; mi < 4; ++mi)
#pragma unroll
        for (int ni = 0; ni < 4; ++ni)
          acc[mi][ni] = MFMA16(af[mi], bfr[ni], acc[mi][ni]);
    }
  }

  float* fo = (mat == 0) ? qo : (mat == 1) ? ko : vo;
  __syncthreads();  // K-loop LDS reads done; smem reusable for V transpose bounce
  unsigned short* T = smem;  // [dh_local][s_local^swz] 128x128 bf16 = 32 KB

#pragma unroll
  for (int mi = 0; mi < 4; ++mi)
#pragma unroll
    for (int ni = 0; ni < 4; ++ni) {
      int col = n0 + wc + ni * 16 + (lane & 15);
      float bs = bias[col];
#pragma unroll
      for (int r = 0; r < 4; ++r) {
        int row = m0 + wr + mi * 16 + ((lane >> 4) << 2) + r;
        float v = acc[mi][ni][r] + bs;
        int b = row >> 10, s = row & 1023, h = col >> 6, dh = col & 63;
        size_t bh = (size_t)(b * HH + h);
        __builtin_nontemporal_store(v, &fo[(bh * SS + s) * DHD + dh]);
        if (mat == 2) {
          int sl = wr + mi * 16 + ((lane >> 4) << 2) + r;
          int dl = wc + ni * 16 + (lane & 15);
          T[dl * 128 + (sl ^ ((dl & 7) << 4))] = f2bf(v);
        } else if (mat == 0) {
          qb[(bh * SS + s) * DHD + dh] = f2bf(v * 0.125f);  // pre-scaled by 1/sqrt(64)
        } else {
          kbf[(bh * SS + s) * DHD + dh] = f2bf(v);
        }
      }
    }

  if (mat == 2) {
    __syncthreads();
    int row = tid >> 1;
    int half = tid & 1;
    int colg = n0 + row;
    int h2 = colg >> 6, dh2 = colg & 63;
    int b = m0 >> 10;
    int sg0 = (m0 & 1023) + half * 64;
    unsigned short* dst = vt + (((size_t)(b * HH + h2)) * DHD + dh2) * SS + sg0;
#pragma unroll
    for (int j = 0; j < 8; ++j) {
      int sc = half * 64 + j * 8;
      bf16x8 vv = *(const bf16x8*)&T[row * 128 + (sc ^ ((row & 7) << 4))];
      *(bf16x8*)(dst + j * 8) = vv;
    }
  }
}

// ------------------------------- K3: fused attention (r15 + NORMAL qk/attn stores)
// Single-variable A/B vs r15: the qk/attn output stores go through L2
// (write-allocate) so the two 64B halves of each 128B line merge before
// eviction; nt (no-allocate) stores were suspected of 2x partial-line write
// amplification at HBM. Deferred-store scheduling kept.
__global__ __launch_bounds__(256) void attn_kernel(
    const unsigned short* __restrict__ qb, const unsigned short* __restrict__ kb,
    const unsigned short* __restrict__ vt, const float* __restrict__ mask,
    float* __restrict__ qk_out, float* __restrict__ attn_out,
    unsigned short* __restrict__ zb) {
  __shared__ __align__(128) unsigned short sbuf[12288];   // 24 KB union
  __shared__ __align__(16) float mbuf[SS];                // 4 KB

  const int tid = threadIdx.x, lane = tid & 63, w = tid >> 6;
  const int fid = blockIdx.x;
  const int s_ = fid >> 3;
  const int qt = s_ & 15;
  const int bh = (fid & 7) + 8 * (s_ >> 4);
  const int b = bh >> 4, h = bh & 15;
  const int r0 = qt * 64 + w * 16;
  const int q15 = lane & 15, G = lane >> 4;

  ((float4*)mbuf)[tid] = ((const float4*)(mask + (size_t)b * SS))[tid];
  __syncthreads();

  bf16x8 aq[2];
  {
    const unsigned short* p = qb + (size_t)bh * SS * DHD + (size_t)(r0 + q15) * DHD + G * 8;
    aq[0] = *(const bf16x8*)p;
    aq[1] = *(const bf16x8*)(p + 32);
  }
  const float mq = mbuf[r0 + q15];

  const unsigned short* kbase = kb + (size_t)bh * SS * DHD;
  const char* vbase = (const char*)(vt + (size_t)bh * DHD * SS);
  float* qrow = qk_out + (size_t)bh * SS * SS + (size_t)(r0 + q15) * SS;
  float* arow = attn_out + (size_t)bh * SS * SS + (size_t)(r0 + q15) * SS;

  float m_run = -INFINITY, l_run = 0.f;

  // ---------------- pass 1: QK^T (KVBLK=128) -> qk (normal, deferred), online (m,l)
  {
    f32x4 dq[8];   // deferred qk tile (held one tile)
    for (int kt = 0; kt < 8; ++kt) {
      int k0 = kt * 128;
      __syncthreads();
#pragma unroll
      for (int i = 0; i < 4; ++i) {   // stage K tile: 128 rows x 64 cols (16 KB)
        unsigned obase = (unsigned)(w * 4096 + i * 1024);
        unsigned a = swz(obase + (unsigned)lane * 16);
        GLOAD16((const char*)(kbase + (size_t)k0 * 64) + a, (char*)sbuf + obase);
      }
      __syncthreads();
      // issue PREVIOUS tile's qk stores now: full compute window to retire
      if (kt > 0) {
        int p0 = (kt - 1) * 128 + G * 4;
#pragma unroll
        for (int ct = 0; ct < 8; ++ct)
          *(f32x4*)(qrow + p0 + ct * 16) = dq[ct];
      }
      f32x4 sm[8];
#pragma unroll
      for (int ct = 0; ct < 8; ++ct) {
        f32x4 acc = {0.f, 0.f, 0.f, 0.f};
#pragma unroll
        for (int ks = 0; ks < 2; ++ks) {
          unsigned a = (unsigned)((ct * 16 + q15) * 128 + ks * 64 + G * 16);
          bf16x8 bk = *(const bf16x8*)((const char*)sbuf + swz(a));
          acc = MFMA16(bk, aq[ks], acc);   // swapped: row=k, col=q
        }
        dq[ct] = acc;
        int c0 = k0 + ct * 16 + G * 4;
        float4 mk4 = *(const float4*)(mbuf + c0);
#pragma unroll
        for (int r = 0; r < 4; ++r) {
          float t = fminf(mq + ((const float*)&mk4)[r], 1.f);
          sm[ct][r] = acc[r] + t * (-1.0e9f);
        }
      }
      float mx = sm[0][0];
#pragma unroll
      for (int ct = 0; ct < 8; ++ct)
#pragma unroll
        for (int r = 0; r < 4; ++r) mx = fmaxf(mx, sm[ct][r]);
      mx = fmaxf(mx, __shfl_xor(mx, 16, 64));
      mx = fmaxf(mx, __shfl_xor(mx, 32, 64));
      float m_new = fmaxf(m_run, mx);
      float es = 0.f;
#pragma unroll
      for (int ct = 0; ct < 8; ++ct)
#pragma unroll
        for (int r = 0; r < 4; ++r) es += __expf(sm[ct][r] - m_new);
      es += __shfl_xor(es, 16, 64);
      es += __shfl_xor(es, 32, 64);
      l_run = l_run * __expf(m_run - m_new) + es;
      m_run = m_new;
    }
    // tail: last tile's qk stores
    int p0 = 7 * 128 + G * 4;
#pragma unroll
    for (int ct = 0; ct < 8; ++ct)
      *(f32x4*)(qrow + p0 + ct * 16) = dq[ct];
  }

  const float inv_l = 1.0f / l_run;

  // ---------------- pass 2: recompute (KVBLK=64) -> attn (normal, deferred), PV
  f32x4 zacc[4];
#pragma unroll
  for (int dt = 0; dt < 4; ++dt) zacc[dt] = (f32x4){0.f, 0.f, 0.f, 0.f};

  unsigned short* kb2 = sbuf;                 // 8 KB
  unsigned short* vb2 = sbuf + 4096;          // 8 KB
  unsigned short* pw  = sbuf + 8192 + w * 1024;  // 2 KB per wave
  const unsigned pswz = (unsigned)((q15 & 14) << 3);

  f32x4 da[4];   // deferred attn tile
  for (int kt = 0; kt < 16; ++kt) {
    int k0 = kt * 64;
    __syncthreads();
#pragma unroll
    for (int i = 0; i < 2; ++i) {
      unsigned obase = (unsigned)(w * 2048 + i * 1024);
      unsigned a = swz(obase + (unsigned)lane * 16);
      GLOAD16((const char*)(kbase + (size_t)k0 * 64) + a, (char*)kb2 + obase);
      GLOAD16(vbase + (size_t)(a >> 7) * (SS * 2) + (size_t)k0 * 2 + (a & 127),
              (char*)vb2 + obase);
    }
    __syncthreads();
    // issue PREVIOUS tile's attn stores now
    if (kt > 0) {
      int p0 = (kt - 1) * 64 + G * 4;
#pragma unroll
      for (int ct = 0; ct < 4; ++ct)
        *(f32x4*)(arow + p0 + ct * 16) = da[ct];
    }
#pragma unroll
    for (int ct = 0; ct < 4; ++ct) {
      f32x4 acc = {0.f, 0.f, 0.f, 0.f};
#pragma unroll
      for (int ks = 0; ks < 2; ++ks) {
        unsigned a = (unsigned)((ct * 16 + q15) * 128 + ks * 64 + G * 16);
        bf16x8 bk = *(const bf16x8*)((const char*)kb2 + swz(a));
        acc = MFMA16(bk, aq[ks], acc);
      }
      int c0 = k0 + ct * 16 + G * 4;
      float4 mk4 = *(const float4*)(mbuf + c0);
      f32x4 pn;
#pragma unroll
      for (int r = 0; r < 4; ++r) {
        float t = fminf(mq + ((const float*)&mk4)[r], 1.f);
        pn[r] = __expf(acc[r] + t * (-1.0e9f) - m_run) * inv_l;
      }
      da[ct] = pn;
      unsigned u0 = (unsigned)f2bf(pn[0]) | ((unsigned)f2bf(pn[1]) << 16);
      unsigned u1 = (unsigned)f2bf(pn[2]) | ((unsigned)f2bf(pn[3]) << 16);
      uint2 pkd = {u0, u1};
      *(uint2*)((char*)pw + (((unsigned)(q15 * 128 + ct * 32 + G * 8)) ^ pswz)) = pkd;
    }
    // PV: A-frag = P[q=lane&15][k=G*8..G*8+7]
    bf16x8 pa[2];
#pragma unroll
    for (int ks = 0; ks < 2; ++ks)
      pa[ks] = *(const bf16x8*)((char*)pw + (((unsigned)(q15 * 128 + ks * 64 + G * 16)) ^ pswz));
#pragma unroll
    for (int dt = 0; dt < 4; ++dt) {
#pragma unroll
      for (int ks = 0; ks < 2; ++ks) {
        unsigned av = (unsigned)((dt * 16 + q15) * 128 + ks * 64 + G * 16);
        bf16x8 bv = *(const bf16x8*)((const char*)vb2 + swz(av));
        zacc[dt] = MFMA16(pa[ks], bv, zacc[dt]);
      }
    }
  }
  // tail: last tile's attn stores
  {
    int p0 = 15 * 64 + G * 4;
#pragma unroll
    for (int ct = 0; ct < 4; ++ct)
      *(f32x4*)(arow + p0 + ct * 16) = da[ct];
  }

  // z epilogue: rows = r0 + G*4 + r, col = dt*16 + q15
#pragma unroll
  for (int dt = 0; dt < 4; ++dt)
#pragma unroll
    for (int r = 0; r < 4; ++r) {
      int srow = r0 + G * 4 + r;
      int dcol = dt * 16 + q15;
      zb[((size_t)b * SS + srow) * DD + h * 64 + dcol] = f2bf(zacc[dt][r]);
    }
}

// ---------------------------------------------------- K4: out = z @ wo + bo
__global__ __launch_bounds__(256) void out_gemm_kernel(
    const unsigned short* __restrict__ zb, const unsigned short* __restrict__ wot,
    const float* __restrict__ bo, float* __restrict__ outp) {
  __shared__ __align__(128) unsigned short As[128 * 64];
  __shared__ __align__(128) unsigned short Bs[128 * 64];
  const int tid = threadIdx.x, lane = tid & 63, w = tid >> 6;
  const int wr = (w >> 1) * 64, wc = (w & 1) * 64;
  const int m0 = blockIdx.x * 128;
  const int n0 = blockIdx.y * 128;

  f32x4 acc[4][4];
  f32x4 z4 = {0.f, 0.f, 0.f, 0.f};
#pragma unroll
  for (int i = 0; i < 4; ++i)
#pragma unroll
    for (int j = 0; j < 4; ++j) acc[i][j] = z4;

  for (int kt = 0; kt < 1024; kt += 64) {
    __syncthreads();
#pragma unroll
    for (int i = 0; i < 4; ++i) {
      unsigned obase = (unsigned)(w * 4096 + i * 1024);
      unsigned a = swz(obase + (unsigned)lane * 16);
      GLOAD16((const char*)zb + ((size_t)(m0 + (int)(a >> 7)) * 1024 + kt) * 2 + (a & 127),
              (char*)As + obase);
      GLOAD16((const char*)wot + ((size_t)(n0 + (int)(a >> 7)) * 1024 + kt) * 2 + (a & 127),
              (char*)Bs + obase);
    }
    __syncthreads();
#pragma unroll
    for (int ks = 0; ks < 2; ++ks) {
      bf16x8 af[4], bfr[4];
#pragma unroll
      for (int mi = 0; mi < 4; ++mi) {
        unsigned a = (unsigned)((wr + mi * 16 + (lane & 15)) * 128 + ks * 64 + ((lane >> 4) * 16));
        af[mi] = *(const bf16x8*)((const char*)As + swz(a));
      }
#pragma unroll
      for (int ni = 0; ni < 4; ++ni) {
        unsigned a = (unsigned)((wc + ni * 16 + (lane & 15)) * 128 + ks * 64 + ((lane >> 4) * 16));
        bfr[ni] = *(const bf16x8*)((const char*)Bs + swz(a));
      }
#pragma unroll
      for (int mi = 0; mi < 4; ++mi)
#pragma unroll
        for (int ni = 0; ni < 4; ++ni)
          acc[mi][ni] = MFMA16(af[mi], bfr[ni], acc[mi][ni]);
    }
  }
#pragma unroll
  for (int mi = 0; mi < 4; ++mi)
#pragma unroll
    for (int ni = 0; ni < 4; ++ni) {
      int col = n0 + wc + ni * 16 + (lane & 15);
      float bs = bo[col];
#pragma unroll
      for (int r = 0; r < 4; ++r) {
        int row = m0 + wr + mi * 16 + ((lane >> 4) << 2) + r;
        __builtin_nontemporal_store(acc[mi][ni][r] + bs, &outp[(size_t)row * DD + col]);
      }
    }
}

// ------------------------------------------------------------------ launcher
extern "C" void kernel_launch(void* const* d_in, const int* in_sizes, int n_in,
                              void* d_out, int out_size, void* d_ws, size_t ws_size,
                              hipStream_t stream) {
  const float* x    = (const float*)d_in[0];
  const float* mask = (const float*)d_in[1];
  const float* wq_w = (const float*)d_in[2];
  const float* wq_b = (const float*)d_in[3];
  const float* wk_w = (const float*)d_in[4];
  const float* wk_b = (const float*)d_in[5];
  const float* wv_w = (const float*)d_in[6];
  const float* wv_b = (const float*)d_in[7];
  const float* wo_w = (const float*)d_in[8];
  const float* wo_b = (const float*)d_in[9];

  float* outp = (float*)d_out;
  float* attn = outp + (size_t)8388608;
  float* qk   = attn + (size_t)134217728;
  float* qo   = qk + (size_t)134217728;
  float* ko   = qo + (size_t)8388608;
  float* vo   = ko + (size_t)8388608;

  char* ws = (char*)d_ws;
  unsigned short* xb  = (unsigned short*)(ws + 0);
  unsigned short* wqt = (unsigned short*)(ws + 16777216);
  unsigned short* wkt = (unsigned short*)(ws + 18874368);
  unsigned short* wvt = (unsigned short*)(ws + 20971520);
  unsigned short* wot = (unsigned short*)(ws + 23068672);
  unsigned short* qb  = (unsigned short*)(ws + 25165824);
  unsigned short* kb  = (unsigned short*)(ws + 41943040);
  unsigned short* vt  = (unsigned short*)(ws + 58720256);
  unsigned short* zb  = (unsigned short*)(ws + 75497472);

  cvt_x_kernel<<<8192, 256, 0, stream>>>(x, xb);
  transpose_w_kernel<<<dim3(32, 32, 4), dim3(32, 8), 0, stream>>>(
      wq_w, wk_w, wv_w, wo_w, wqt, wkt, wvt, wot);
  proj_gemm_kernel<<<1536, 256, 0, stream>>>(
      xb, wqt, wkt, wvt, wq_b, wk_b, wv_b, qo, ko, vo, qb, kb, vt);
  attn_kernel<<<2048, 256, 0, stream>>>(qb, kb, vt, mask, qk, attn, zb);
  out_gemm_kernel<<<dim3(64, 8), 256, 0, stream>>>(zb, wot, wo_b, outp);
}